// Round 11
// baseline (293.965 us; speedup 1.0000x reference)
//
#include <hip/hip_runtime.h>
#include <hip/hip_bf16.h>
#include <math.h>

#define T_DIM 2048
#define K_DIM 17
#define HID   64
#define B_DIM 32

typedef short s16x8 __attribute__((ext_vector_type(8)));
typedef unsigned u32x2 __attribute__((ext_vector_type(2)));
typedef float f32x4 __attribute__((ext_vector_type(4)));

__device__ __forceinline__ float bf2f(short u) {
    unsigned v = ((unsigned)(unsigned short)u) << 16;
    return __builtin_bit_cast(float, v);
}
__device__ __forceinline__ short f2bf(float f) {          // cold path
    __hip_bfloat16 h = __float2bfloat16(f);
    return __builtin_bit_cast(short, h);
}
__device__ __forceinline__ short f2bf_fast(float f) {
    unsigned u = __builtin_bit_cast(unsigned, f);
    return (short)((u + 0x8000u) >> 16);
}
__device__ __forceinline__ unsigned pk2bf(float lo, float hi) {
    unsigned ul = __builtin_bit_cast(unsigned, lo);
    unsigned uh = __builtin_bit_cast(unsigned, hi);
    return ((ul + 0x8000u) >> 16) | ((uh + 0x8000u) & 0xFFFF0000u);
}

// COCO skeleton sparsity: column-v nonzeros of adj (incl. self).
static constexpr int NBR_PTR[18] = {0,3,6,9,11,13,17,21,24,27,29,31,34,37,40,43,45,47};
static constexpr int NBR_K[47] = {
    0,1,2,  0,1,3,  0,2,4,  1,3,  2,4,
    5,6,7,11,  5,6,8,12,  5,7,9,  6,8,10,  7,9,  8,10,
    5,11,13,  6,12,14,  11,13,15,  12,14,16,  13,15,  14,16 };

// ---------------------------------------------------------------------------
// Fold GCN channel-mix into temporal conv weights (bf16).
//   effT0[o][k32]  k = dt*8+cin (cin<3, dt<3), rest 0    (block1, K=32)
//   effT12[blk][o][dt*64+c]                              (blocks 2,3, K=192)
//   bnc[blk*64+o] = s/sqrt(v+eps);  bnc[192+blk*64+o] = b - m*inv
// ---------------------------------------------------------------------------
__global__ void fold_weights_kernel(
    const float* __restrict__ gw0, const float* __restrict__ gw1,
    const float* __restrict__ gw2, const float* __restrict__ tcn,
    const float* __restrict__ bns, const float* __restrict__ bnb,
    const float* __restrict__ bnm, const float* __restrict__ bnv,
    short* __restrict__ effT0, short* __restrict__ effT12,
    float* __restrict__ bnc)
{
    int tid = blockIdx.x * blockDim.x + threadIdx.x;
    int stride = gridDim.x * blockDim.x;
    for (int idx = tid; idx < 2048; idx += stride) {
        int o = idx >> 5, k = idx & 31, dt = k >> 3, cin = k & 7;
        float s = 0.f;
        if (dt < 3 && cin < 3)
            for (int m = 0; m < 64; m++)
                s += gw0[cin * 64 + m] * tcn[(o * 64 + m) * 3 + dt];
        effT0[idx] = f2bf(s);
    }
    for (int idx = tid; idx < 24576; idx += stride) {
        int blk = idx / 12288;
        int r = idx - blk * 12288;
        int o = r / 192, k = r - o * 192, dt = k >> 6, c = k & 63;
        const float* gw = blk ? gw2 : gw1;
        const float* tw = tcn + (size_t)(blk + 1) * 64 * 64 * 3;
        float s = 0.f;
        for (int m = 0; m < 64; m++)
            s += gw[c * 64 + m] * tw[(o * 64 + m) * 3 + dt];
        effT12[idx] = f2bf(s);
    }
    for (int i = tid; i < 192; i += stride) {
        float inv = bns[i] * rsqrtf(bnv[i] + 1e-5f);
        bnc[i] = inv;
        bnc[192 + i] = bnb[i] - bnm[i] * inv;
    }
}

// ---------------------------------------------------------------------------
// Kernel A: blocks 1+2 fused, adjacency-last, y1 lives only in LDS.
// TT=8 output t's.  ybuf rows = (t - (t0-1))*17 + v, 170 rows x 72 pitch.
// Phases: stage xt | GEMM1 (B gathered from xt) -> z1 | mix1 in-place (y1)
//         | GEMM2 (B=ybuf) acc in regs + residual preload | z2 -> ybuf
//         | mix2 + residual + coalesced full-line y2 store.
// m-tile-per-wave: weight frags = 24 VGPR, each wave owns 16 o's.
// LDS ~27.5 KB, VGPR ~64 -> (256,5) gives 5 WG/CU without remat pressure.
// ---------------------------------------------------------------------------
__global__ __launch_bounds__(256, 5) void stgcn_ab_kernel(
    const float* __restrict__ x, const float* __restrict__ adj,
    const short* __restrict__ effT0, const short* __restrict__ effT12,
    const float* __restrict__ bnc, short* __restrict__ y2)
{
    __shared__ float adj_s[289];
    __shared__ __align__(16) float xt[12 * 51];        // 2448 B
    __shared__ __align__(16) short ybuf[170 * 72];     // 24480 B

    const int tid = threadIdx.x;
    const int b = blockIdx.y;
    const int t0 = blockIdx.x * 8;
    const int lane = tid & 63, wave = tid >> 6;
    const int col = lane & 15, kgrp = lane >> 4;

    for (int i = tid; i < 289; i += 256) adj_s[i] = adj[i];
    {
        const int tbase = t0 - 2;
        const float* xb = x + (size_t)(b * T_DIM + tbase) * 51;
        for (int i = tid; i < 612; i += 256) {
            int tt = tbase + i / 51;
            xt[i] = (tt >= 0 && tt < T_DIM) ? xb[i] : 0.f;
        }
    }
    // weight A-frags (m-tile per wave: o = wave*16 + col)
    s16x8 af1 = *(const s16x8*)(effT0 + (wave * 16 + col) * 32 + kgrp * 8);
    s16x8 af2[6];
    #pragma unroll
    for (int kk = 0; kk < 6; kk++)
        af2[kk] = *(const s16x8*)(effT12 +
            (wave * 16 + col) * 192 + kk * 32 + kgrp * 8);
    __syncthreads();

    // ---- GEMM1: 170 rows (11 tiles), K=32; B per-lane gathered from xt ----
    for (int tile = 0; tile < 11; tile++) {
        const int r = tile * 16 + col;
        const int me = r < 170 ? r : 169;
        const int s = (me * 241) >> 12;     // me/17
        const int k = me - s * 17;
        s16x8 bfr = (s16x8){0,0,0,0,0,0,0,0};
        if (kgrp < 3) {                      // dt = kgrp
            const float* xp = &xt[(s + kgrp) * 51 + k * 3];
            bfr[0] = f2bf_fast(xp[0]);
            bfr[1] = f2bf_fast(xp[1]);
            bfr[2] = f2bf_fast(xp[2]);
        }
        f32x4 acc = __builtin_amdgcn_mfma_f32_16x16x32_bf16(
            af1, bfr, (f32x4){0.f, 0.f, 0.f, 0.f}, 0, 0, 0);
        if (r < 170) {
            u32x2 st;
            st[0] = pk2bf(acc[0], acc[1]);
            st[1] = pk2bf(acc[2], acc[3]);
            *(u32x2*)&ybuf[r * 72 + wave * 16 + kgrp * 4] = st;
        }
    }
    __syncthreads();

    // ---- mix1 (in-place): y1 = relu(bn1(sum_k adj * z1)), zero OOB t ----
    for (int idx = tid; idx < 320; idx += 256) {
        const int tl = idx >> 5, oq = idx & 31, o0 = oq * 2;
        const int t = t0 - 1 + tl;
        const bool valid = (t >= 0) && (t < T_DIM);
        const float inv0 = bnc[o0], inv1 = bnc[o0 + 1];
        const float sh0 = bnc[192 + o0], sh1 = bnc[192 + o0 + 1];
        float zk0[17], zk1[17];
        #pragma unroll
        for (int k = 0; k < 17; k++) {
            unsigned u = *(const unsigned*)&ybuf[(tl * 17 + k) * 72 + o0];
            zk0[k] = bf2f((short)(u & 0xFFFF));
            zk1[k] = bf2f((short)(u >> 16));
        }
        #pragma unroll
        for (int v = 0; v < 17; v++) {
            float g0 = 0.f, g1 = 0.f;
            #pragma unroll
            for (int e = NBR_PTR[v]; e < NBR_PTR[v + 1]; e++) {
                int k = NBR_K[e];
                float w = adj_s[k * 17 + v];
                g0 += w * zk0[k]; g1 += w * zk1[k];
            }
            float v0 = valid ? fmaxf(g0 * inv0 + sh0, 0.f) : 0.f;
            float v1 = valid ? fmaxf(g1 * inv1 + sh1, 0.f) : 0.f;
            *(unsigned*)&ybuf[(tl * 17 + v) * 72 + o0] = pk2bf(v0, v1);
        }
    }
    __syncthreads();

    // ---- GEMM2: 136 rows (9 tiles), K=192, acc in regs ----
    f32x4 acc2[9];
    #pragma unroll
    for (int t2 = 0; t2 < 9; t2++) acc2[t2] = (f32x4){0.f, 0.f, 0.f, 0.f};
    #pragma unroll
    for (int kk = 0; kk < 6; kk++) {
        #pragma unroll
        for (int t2 = 0; t2 < 9; t2++) {
            const int r = t2 * 16 + col;
            const int me = r < 136 ? r : 135;
            s16x8 bfr = *(const s16x8*)&ybuf[
                (me + 17 * (kk >> 1)) * 72 + (kk & 1) * 32 + kgrp * 8];
            acc2[t2] = __builtin_amdgcn_mfma_f32_16x16x32_bf16(
                af2[kk], bfr, acc2[t2], 0, 0, 0);
        }
    }
    // residual preload (y1 rows 17..152) into regs before overwrite
    unsigned rv[17];
    {
        const int tl = tid >> 5, o0 = (tid & 31) * 2;
        #pragma unroll
        for (int v = 0; v < 17; v++)
            rv[v] = *(const unsigned*)&ybuf[((tl + 1) * 17 + v) * 72 + o0];
    }
    __syncthreads();

    // ---- z2 -> ybuf rows 0..135 ----
    #pragma unroll
    for (int t2 = 0; t2 < 9; t2++) {
        const int r = t2 * 16 + col;
        if (r < 136) {
            u32x2 st;
            st[0] = pk2bf(acc2[t2][0], acc2[t2][1]);
            st[1] = pk2bf(acc2[t2][2], acc2[t2][3]);
            *(u32x2*)&ybuf[r * 72 + wave * 16 + kgrp * 4] = st;
        }
    }
    __syncthreads();

    // ---- mix2 + residual + coalesced y2 store ----
    {
        const int tl = tid >> 5, o0 = (tid & 31) * 2;
        const float inv0 = bnc[64 + o0], inv1 = bnc[64 + o0 + 1];
        const float sh0 = bnc[256 + o0], sh1 = bnc[256 + o0 + 1];
        float zk0[17], zk1[17];
        #pragma unroll
        for (int k = 0; k < 17; k++) {
            unsigned u = *(const unsigned*)&ybuf[(tl * 17 + k) * 72 + o0];
            zk0[k] = bf2f((short)(u & 0xFFFF));
            zk1[k] = bf2f((short)(u >> 16));
        }
        const size_t gout = ((size_t)(b * T_DIM + t0 + tl) * K_DIM) * 64;
        #pragma unroll
        for (int v = 0; v < 17; v++) {
            float g0 = 0.f, g1 = 0.f;
            #pragma unroll
            for (int e = NBR_PTR[v]; e < NBR_PTR[v + 1]; e++) {
                int k = NBR_K[e];
                float w = adj_s[k * 17 + v];
                g0 += w * zk0[k]; g1 += w * zk1[k];
            }
            float v0 = fmaxf(g0 * inv0 + sh0, 0.f) + bf2f((short)(rv[v] & 0xFFFF));
            float v1 = fmaxf(g1 * inv1 + sh1, 0.f) + bf2f((short)(rv[v] >> 16));
            *(unsigned*)&y2[gout + (size_t)v * 64 + o0] = pk2bf(v0, v1);
        }
    }
}

// ---------------------------------------------------------------------------
// Kernel B: block 3 (DIL=2) + pool.  Coalesced-stage y2 tile (12 t x 17 k)
// into LDS; GEMM3 acc in regs; residual pre-summed to 2 regs; z3 overwrites
// stage after barrier; mix3 + pool -> part.
// Pool scratch pr aliased into dead ybuf tail (rows >=136 are free after the
// residual-presum barrier) -> LDS ~30.5 KB -> 5 WG/CU with (256,5).
// ---------------------------------------------------------------------------
__global__ __launch_bounds__(256, 5) void stgcn_c_kernel(
    const short* __restrict__ y2, const float* __restrict__ adj,
    const short* __restrict__ effW3, const float* __restrict__ bnc,
    float* __restrict__ part, int b0)
{
    __shared__ float adj_s[289];
    __shared__ __align__(16) short ybuf[204 * 72];     // 29376 B

    float* pr = (float*)&ybuf[136 * 72];   // alias: rows 136.. free at pool time

    const int tid = threadIdx.x;
    const int b = blockIdx.y;
    const int t0 = blockIdx.x * 8;
    const int lane = tid & 63, wave = tid >> 6;
    const int col = lane & 15, kgrp = lane >> 4;

    for (int i = tid; i < 289; i += 256) adj_s[i] = adj[i];
    s16x8 af3[6];
    #pragma unroll
    for (int kk = 0; kk < 6; kk++)
        af3[kk] = *(const s16x8*)(effW3 +
            (wave * 16 + col) * 192 + kk * 32 + kgrp * 8);

    // coalesced stage: rows (t0-2 .. t0+9) x 17 k, zero-fill OOB
    {
        const int bLo = b * (T_DIM * 17);
        const int bHi = bLo + T_DIM * 17;
        const int g0r = bLo + (t0 - 2) * 17;
        for (int idx = tid; idx < 1632; idx += 256) {
            const int row = idx >> 3, c = idx & 7;
            const int gr = g0r + row;
            s16x8 v = (s16x8){0,0,0,0,0,0,0,0};
            if (gr >= bLo && gr < bHi)
                v = *(const s16x8*)(y2 + (size_t)gr * 64 + c * 8);
            *(s16x8*)&ybuf[row * 72 + c * 8] = v;
        }
    }
    __syncthreads();

    // ---- GEMM3: 136 rows (9 tiles), K=192, DIL=2, acc in regs ----
    f32x4 acc3[9];
    #pragma unroll
    for (int t3 = 0; t3 < 9; t3++) acc3[t3] = (f32x4){0.f, 0.f, 0.f, 0.f};
    #pragma unroll
    for (int kk = 0; kk < 6; kk++) {
        #pragma unroll
        for (int t3 = 0; t3 < 9; t3++) {
            const int r = t3 * 16 + col;
            const int me = r < 136 ? r : 135;
            s16x8 bfr = *(const s16x8*)&ybuf[
                (me + 34 * (kk >> 1)) * 72 + (kk & 1) * 32 + kgrp * 8];
            acc3[t3] = __builtin_amdgcn_mfma_f32_16x16x32_bf16(
                af3[kk], bfr, acc3[t3], 0, 0, 0);
        }
    }
    // residual pre-sum (rows 34..169 = y2[t0..t0+7]) -> 2 regs
    float rs0 = 0.f, rs1 = 0.f;
    {
        const int tl = tid >> 5, o0 = (tid & 31) * 2;
        #pragma unroll
        for (int v = 0; v < 17; v++) {
            unsigned u = *(const unsigned*)&ybuf[((tl + 2) * 17 + v) * 72 + o0];
            rs0 += bf2f((short)(u & 0xFFFF));
            rs1 += bf2f((short)(u >> 16));
        }
    }
    __syncthreads();

    // ---- z3 -> ybuf rows 0..135 ----
    #pragma unroll
    for (int t3 = 0; t3 < 9; t3++) {
        const int r = t3 * 16 + col;
        if (r < 136) {
            u32x2 st;
            st[0] = pk2bf(acc3[t3][0], acc3[t3][1]);
            st[1] = pk2bf(acc3[t3][2], acc3[t3][3]);
            *(u32x2*)&ybuf[r * 72 + wave * 16 + kgrp * 4] = st;
        }
    }
    __syncthreads();

    // ---- mix3 + pool ----
    {
        const int tl = tid >> 5, o0 = (tid & 31) * 2;
        const float inv0 = bnc[128 + o0], inv1 = bnc[128 + o0 + 1];
        const float sh0 = bnc[320 + o0], sh1 = bnc[320 + o0 + 1];
        float zk0[17], zk1[17];
        #pragma unroll
        for (int k = 0; k < 17; k++) {
            unsigned u = *(const unsigned*)&ybuf[(tl * 17 + k) * 72 + o0];
            zk0[k] = bf2f((short)(u & 0xFFFF));
            zk1[k] = bf2f((short)(u >> 16));
        }
        float ps0 = rs0, ps1 = rs1;
        #pragma unroll
        for (int v = 0; v < 17; v++) {
            float g0 = 0.f, g1 = 0.f;
            #pragma unroll
            for (int e = NBR_PTR[v]; e < NBR_PTR[v + 1]; e++) {
                int k = NBR_K[e];
                float w = adj_s[k * 17 + v];
                g0 += w * zk0[k]; g1 += w * zk1[k];
            }
            ps0 += fmaxf(g0 * inv0 + sh0, 0.f);
            ps1 += fmaxf(g1 * inv1 + sh1, 0.f);
        }
        *(float2*)&pr[tl * 64 + o0] = make_float2(ps0, ps1);
    }
    __syncthreads();
    if (tid < 64) {
        float s = 0.f;
        #pragma unroll
        for (int i = 0; i < 8; i++) s += pr[i * 64 + tid];
        part[((size_t)(b0 + b) * 256 + blockIdx.x) * 64 + tid] = s;
    }
}

// ---------------------------------------------------------------------------
// Sum 256 partials per (b,c) with 256 threads, mean, LayerNorm, FC.
// ---------------------------------------------------------------------------
__global__ __launch_bounds__(256) void finish_kernel(
    const float* __restrict__ part, const float* __restrict__ ln_s,
    const float* __restrict__ ln_b, const float* __restrict__ fc_w,
    const float* __restrict__ fc_b, float* __restrict__ out)
{
    __shared__ float red[4][64];
    __shared__ float ns[64];
    const int b = blockIdx.x;
    const int g = threadIdx.x >> 6, c = threadIdx.x & 63;
    float s = 0.f;
    for (int j = 0; j < 64; j++)
        s += part[((size_t)b * 256 + g * 64 + j) * 64 + c];
    red[g][c] = s;
    __syncthreads();
    if (threadIdx.x < 64) {
        float feat = (red[0][c] + red[1][c] + red[2][c] + red[3][c])
                   / (float)(T_DIM * K_DIM);
        float m = feat;
        #pragma unroll
        for (int off = 32; off > 0; off >>= 1) m += __shfl_down(m, off);
        m = __shfl(m, 0) / 64.f;
        float d = feat - m;
        float v = d * d;
        #pragma unroll
        for (int off = 32; off > 0; off >>= 1) v += __shfl_down(v, off);
        v = __shfl(v, 0) / 64.f;
        ns[c] = d * rsqrtf(v + 1e-5f) * ln_s[c] + ln_b[c];
    }
    __syncthreads();
    if (threadIdx.x < 10) {
        float o = fc_b[threadIdx.x];
        for (int i = 0; i < 64; i++) o += ns[i] * fc_w[i * 10 + threadIdx.x];
        out[b * 10 + threadIdx.x] = o;
    }
}

// ---------------------------------------------------------------------------
extern "C" void kernel_launch(void* const* d_in, const int* in_sizes, int n_in,
                              void* d_out, int out_size, void* d_ws, size_t ws_size,
                              hipStream_t stream)
{
    const float* kpts = (const float*)d_in[0];
    const float* adj  = (const float*)d_in[1];
    const float* gw0  = (const float*)d_in[2];
    const float* gw1  = (const float*)d_in[3];
    const float* gw2  = (const float*)d_in[4];
    const float* tcn  = (const float*)d_in[5];
    const float* bns  = (const float*)d_in[6];
    const float* bnb  = (const float*)d_in[7];
    const float* bnm  = (const float*)d_in[8];
    const float* bnv  = (const float*)d_in[9];
    const float* lns  = (const float*)d_in[10];
    const float* lnb  = (const float*)d_in[11];
    const float* fcw  = (const float*)d_in[12];
    const float* fcb  = (const float*)d_in[13];
    float* out = (float*)d_out;

    // ws: bnc(384 f) | part(32*256*64 f) | effT0(2048 s) | effT12(24576 s) | y2
    float* bnc  = (float*)d_ws;
    float* part = bnc + 384;
    short* effT0  = (short*)(part + (size_t)B_DIM * 256 * 64);
    short* effT12 = effT0 + 2048;
    short* y2     = effT12 + 24576;
    const size_t fixed_bytes = 384 * 4 + (size_t)B_DIM * 256 * 64 * 4
                             + 2048 * 2 + 24576 * 2;          // ~2.15 MB
    const size_t y_per_b = (size_t)T_DIM * K_DIM * 64 * 2;    // 4,456,448 B

    int cb = B_DIM;                 // single y2 buffer: cb=32 needs ~145 MB
    while (cb > 1 && fixed_bytes + (size_t)cb * y_per_b > ws_size) cb >>= 1;

    fold_weights_kernel<<<64, 256, 0, stream>>>(gw0, gw1, gw2, tcn,
                                                bns, bnb, bnm, bnv,
                                                effT0, effT12, bnc);

    for (int b0 = 0; b0 < B_DIM; b0 += cb) {
        stgcn_ab_kernel<<<dim3(T_DIM / 8, cb), 256, 0, stream>>>(
            kpts + (size_t)b0 * T_DIM * K_DIM * 3, adj, effT0, effT12, bnc, y2);
        stgcn_c_kernel<<<dim3(T_DIM / 8, cb), 256, 0, stream>>>(
            y2, adj, effT12 + 12288, bnc, part, b0);
    }

    finish_kernel<<<B_DIM, 256, 0, stream>>>(part, lns, lnb, fcw, fcb, out);
}

// Round 12
// 265.639 us; speedup vs baseline: 1.1066x; 1.1066x over previous
//
#include <hip/hip_runtime.h>
#include <hip/hip_bf16.h>
#include <math.h>

#define T_DIM 2048
#define K_DIM 17
#define HID   64
#define B_DIM 32

typedef short s16x8 __attribute__((ext_vector_type(8)));
typedef unsigned u32x2 __attribute__((ext_vector_type(2)));
typedef float f32x4 __attribute__((ext_vector_type(4)));

__device__ __forceinline__ float bf2f(short u) {
    unsigned v = ((unsigned)(unsigned short)u) << 16;
    return __builtin_bit_cast(float, v);
}
__device__ __forceinline__ short f2bf(float f) {          // cold path
    __hip_bfloat16 h = __float2bfloat16(f);
    return __builtin_bit_cast(short, h);
}
__device__ __forceinline__ short f2bf_fast(float f) {
    unsigned u = __builtin_bit_cast(unsigned, f);
    return (short)((u + 0x8000u) >> 16);
}
__device__ __forceinline__ unsigned pk2bf(float lo, float hi) {
    unsigned ul = __builtin_bit_cast(unsigned, lo);
    unsigned uh = __builtin_bit_cast(unsigned, hi);
    return ((ul + 0x8000u) >> 16) | ((uh + 0x8000u) & 0xFFFF0000u);
}

// COCO skeleton sparsity: column-v nonzeros of adj (incl. self).
// constexpr copies for compile-time-unrolled loops; __device__ copies for
// runtime-indexed loops.
static constexpr int NBR_PTR[18] = {0,3,6,9,11,13,17,21,24,27,29,31,34,37,40,43,45,47};
static constexpr int NBR_K[47] = {
    0,1,2,  0,1,3,  0,2,4,  1,3,  2,4,
    5,6,7,11,  5,6,8,12,  5,7,9,  6,8,10,  7,9,  8,10,
    5,11,13,  6,12,14,  11,13,15,  12,14,16,  13,15,  14,16 };
__device__ const int d_NBR_PTR[18] = {0,3,6,9,11,13,17,21,24,27,29,31,34,37,40,43,45,47};
__device__ const int d_NBR_K[47] = {
    0,1,2,  0,1,3,  0,2,4,  1,3,  2,4,
    5,6,7,11,  5,6,8,12,  5,7,9,  6,8,10,  7,9,  8,10,
    5,11,13,  6,12,14,  11,13,15,  12,14,16,  13,15,  14,16 };

// ---------------------------------------------------------------------------
// Fold GCN channel-mix into temporal conv weights (bf16).
//   effT0[o][k32]  k = dt*8+cin (cin<3, dt<3), rest 0    (block1, K=32)
//   effT12[blk][o][dt*64+c]                              (blocks 2,3, K=192)
//   bnc[blk*64+o] = s/sqrt(v+eps);  bnc[192+blk*64+o] = b - m*inv
// ---------------------------------------------------------------------------
__global__ void fold_weights_kernel(
    const float* __restrict__ gw0, const float* __restrict__ gw1,
    const float* __restrict__ gw2, const float* __restrict__ tcn,
    const float* __restrict__ bns, const float* __restrict__ bnb,
    const float* __restrict__ bnm, const float* __restrict__ bnv,
    short* __restrict__ effT0, short* __restrict__ effT12,
    float* __restrict__ bnc)
{
    int tid = blockIdx.x * blockDim.x + threadIdx.x;
    int stride = gridDim.x * blockDim.x;
    for (int idx = tid; idx < 2048; idx += stride) {
        int o = idx >> 5, k = idx & 31, dt = k >> 3, cin = k & 7;
        float s = 0.f;
        if (dt < 3 && cin < 3)
            for (int m = 0; m < 64; m++)
                s += gw0[cin * 64 + m] * tcn[(o * 64 + m) * 3 + dt];
        effT0[idx] = f2bf(s);
    }
    for (int idx = tid; idx < 24576; idx += stride) {
        int blk = idx / 12288;
        int r = idx - blk * 12288;
        int o = r / 192, k = r - o * 192, dt = k >> 6, c = k & 63;
        const float* gw = blk ? gw2 : gw1;
        const float* tw = tcn + (size_t)(blk + 1) * 64 * 64 * 3;
        float s = 0.f;
        for (int m = 0; m < 64; m++)
            s += gw[c * 64 + m] * tw[(o * 64 + m) * 3 + dt];
        effT12[idx] = f2bf(s);
    }
    for (int i = tid; i < 192; i += stride) {
        float inv = bns[i] * rsqrtf(bnv[i] + 1e-5f);
        bnc[i] = inv;
        bnc[192 + i] = bnb[i] - bnm[i] * inv;
    }
}

// ---------------------------------------------------------------------------
// Kernel A: blocks 1+2 fused.  Block1 adjacency-FIRST (graph premix on the
// 3-channel input — 6x cheaper than a 64-channel mix), block2 adjacency-last.
// Phases: stage xt | gc-premix xt->xtg (3ch) | GEMM1 (B gathered from xtg,
// BN+ReLU in epilogue) -> y1 in ybuf | GEMM2 acc regs + residual preload |
// z2 -> ybuf | mix2 + residual + coalesced y2 store.
// LDS ~30.6 KB -> up to 5 WG/CU; (256,4) keeps VGPR cap 128 (no spill —
// R11's (256,5) spilled: VGPR 48, 145 MB scratch fetch).
// ---------------------------------------------------------------------------
__global__ __launch_bounds__(256, 4) void stgcn_ab_kernel(
    const float* __restrict__ x, const float* __restrict__ adj,
    const short* __restrict__ effT0, const short* __restrict__ effT12,
    const float* __restrict__ bnc, short* __restrict__ y2)
{
    __shared__ float adj_s[289];
    __shared__ __align__(16) float xt[12 * 51];        // 2448 B
    __shared__ __align__(16) float xtg[12 * 51];       // 2448 B (premixed)
    __shared__ __align__(16) short ybuf[170 * 72];     // 24480 B

    const int tid = threadIdx.x;
    const int b = blockIdx.y;
    const int t0 = blockIdx.x * 8;
    const int lane = tid & 63, wave = tid >> 6;
    const int col = lane & 15, kgrp = lane >> 4;

    for (int i = tid; i < 289; i += 256) adj_s[i] = adj[i];
    {
        const int tbase = t0 - 2;
        const float* xb = x + (size_t)(b * T_DIM + tbase) * 51;
        for (int i = tid; i < 612; i += 256) {
            int tt = tbase + i / 51;
            xt[i] = (tt >= 0 && tt < T_DIM) ? xb[i] : 0.f;
        }
    }
    // weight A-frags (m-tile per wave: o = wave*16 + col)
    s16x8 af1 = *(const s16x8*)(effT0 + (wave * 16 + col) * 32 + kgrp * 8);
    s16x8 af2[6];
    #pragma unroll
    for (int kk = 0; kk < 6; kk++)
        af2[kk] = *(const s16x8*)(effT12 +
            (wave * 16 + col) * 192 + kk * 32 + kgrp * 8);
    __syncthreads();

    // ---- gc-premix: xtg[u][j][c] = sum_k adj[k][j] * xt[u][k][c] ----
    for (int it = tid; it < 612; it += 256) {
        const int u = it / 51;
        const int rem = it - u * 51;
        const int j = rem / 3, c = rem - j * 3;
        float acc = 0.f;
        const int p0 = d_NBR_PTR[j], p1 = d_NBR_PTR[j + 1];
        for (int e = p0; e < p1; e++) {
            int k = d_NBR_K[e];
            acc += adj_s[k * 17 + j] * xt[u * 51 + k * 3 + c];
        }
        xtg[it] = acc;
    }
    __syncthreads();

    // ---- GEMM1: 170 rows (11 tiles), K=32; B gathered from xtg;
    //      epilogue BN+ReLU(+OOB-t zero) -> y1 rows in ybuf ----
    {
        f32x4 inv4 = *(const f32x4*)&bnc[wave * 16 + kgrp * 4];
        f32x4 sh4  = *(const f32x4*)&bnc[192 + wave * 16 + kgrp * 4];
        for (int tile = 0; tile < 11; tile++) {
            const int r = tile * 16 + col;
            const int me = r < 170 ? r : 169;
            const int s = (me * 241) >> 12;     // me/17
            const int j = me - s * 17;
            s16x8 bfr = (s16x8){0,0,0,0,0,0,0,0};
            if (kgrp < 3) {                      // dt = kgrp
                const float* xp = &xtg[(s + kgrp) * 51 + j * 3];
                bfr[0] = f2bf_fast(xp[0]);
                bfr[1] = f2bf_fast(xp[1]);
                bfr[2] = f2bf_fast(xp[2]);
            }
            f32x4 acc = __builtin_amdgcn_mfma_f32_16x16x32_bf16(
                af1, bfr, (f32x4){0.f, 0.f, 0.f, 0.f}, 0, 0, 0);
            const int t = t0 - 1 + s;
            const bool valid = (t >= 0) && (t < T_DIM);
            if (r < 170) {
                float v0 = valid ? fmaxf(acc[0] * inv4[0] + sh4[0], 0.f) : 0.f;
                float v1 = valid ? fmaxf(acc[1] * inv4[1] + sh4[1], 0.f) : 0.f;
                float v2 = valid ? fmaxf(acc[2] * inv4[2] + sh4[2], 0.f) : 0.f;
                float v3 = valid ? fmaxf(acc[3] * inv4[3] + sh4[3], 0.f) : 0.f;
                u32x2 st; st[0] = pk2bf(v0, v1); st[1] = pk2bf(v2, v3);
                *(u32x2*)&ybuf[r * 72 + wave * 16 + kgrp * 4] = st;
            }
        }
    }
    __syncthreads();

    // ---- GEMM2: 136 rows (9 tiles), K=192, acc in regs ----
    f32x4 acc2[9];
    #pragma unroll
    for (int t2 = 0; t2 < 9; t2++) acc2[t2] = (f32x4){0.f, 0.f, 0.f, 0.f};
    #pragma unroll
    for (int kk = 0; kk < 6; kk++) {
        #pragma unroll
        for (int t2 = 0; t2 < 9; t2++) {
            const int r = t2 * 16 + col;
            const int me = r < 136 ? r : 135;
            s16x8 bfr = *(const s16x8*)&ybuf[
                (me + 17 * (kk >> 1)) * 72 + (kk & 1) * 32 + kgrp * 8];
            acc2[t2] = __builtin_amdgcn_mfma_f32_16x16x32_bf16(
                af2[kk], bfr, acc2[t2], 0, 0, 0);
        }
    }
    // residual preload (y1 rows 17..152) into regs before overwrite
    unsigned rv[17];
    {
        const int tl = tid >> 5, o0 = (tid & 31) * 2;
        #pragma unroll
        for (int v = 0; v < 17; v++)
            rv[v] = *(const unsigned*)&ybuf[((tl + 1) * 17 + v) * 72 + o0];
    }
    __syncthreads();

    // ---- z2 -> ybuf rows 0..135 ----
    #pragma unroll
    for (int t2 = 0; t2 < 9; t2++) {
        const int r = t2 * 16 + col;
        if (r < 136) {
            u32x2 st;
            st[0] = pk2bf(acc2[t2][0], acc2[t2][1]);
            st[1] = pk2bf(acc2[t2][2], acc2[t2][3]);
            *(u32x2*)&ybuf[r * 72 + wave * 16 + kgrp * 4] = st;
        }
    }
    __syncthreads();

    // ---- mix2 + residual + coalesced y2 store ----
    {
        const int tl = tid >> 5, o0 = (tid & 31) * 2;
        const float inv0 = bnc[64 + o0], inv1 = bnc[64 + o0 + 1];
        const float sh0 = bnc[256 + o0], sh1 = bnc[256 + o0 + 1];
        float zk0[17], zk1[17];
        #pragma unroll
        for (int k = 0; k < 17; k++) {
            unsigned u = *(const unsigned*)&ybuf[(tl * 17 + k) * 72 + o0];
            zk0[k] = bf2f((short)(u & 0xFFFF));
            zk1[k] = bf2f((short)(u >> 16));
        }
        const size_t gout = ((size_t)(b * T_DIM + t0 + tl) * K_DIM) * 64;
        #pragma unroll
        for (int v = 0; v < 17; v++) {
            float g0 = 0.f, g1 = 0.f;
            #pragma unroll
            for (int e = NBR_PTR[v]; e < NBR_PTR[v + 1]; e++) {
                int k = NBR_K[e];
                float w = adj_s[k * 17 + v];
                g0 += w * zk0[k]; g1 += w * zk1[k];
            }
            float v0 = fmaxf(g0 * inv0 + sh0, 0.f) + bf2f((short)(rv[v] & 0xFFFF));
            float v1 = fmaxf(g1 * inv1 + sh1, 0.f) + bf2f((short)(rv[v] >> 16));
            *(unsigned*)&y2[gout + (size_t)v * 64 + o0] = pk2bf(v0, v1);
        }
    }
}

// ---------------------------------------------------------------------------
// Kernel B: block 3 (DIL=2) + pool.  Coalesced-stage y2 tile (12 t x 17 k)
// into LDS; GEMM3 acc in regs; residual pre-summed to 2 regs; z3 overwrites
// stage after barrier; mix3 + pool -> part.  pr aliased into dead ybuf tail.
// (256,4): VGPR cap 128, no spill; LDS 29.4 KB allows 5 resident WGs.
// ---------------------------------------------------------------------------
__global__ __launch_bounds__(256, 4) void stgcn_c_kernel(
    const short* __restrict__ y2, const float* __restrict__ adj,
    const short* __restrict__ effW3, const float* __restrict__ bnc,
    float* __restrict__ part, int b0)
{
    __shared__ float adj_s[289];
    __shared__ __align__(16) short ybuf[204 * 72];     // 29376 B

    float* pr = (float*)&ybuf[136 * 72];   // alias: rows 136.. free at pool time

    const int tid = threadIdx.x;
    const int b = blockIdx.y;
    const int t0 = blockIdx.x * 8;
    const int lane = tid & 63, wave = tid >> 6;
    const int col = lane & 15, kgrp = lane >> 4;

    for (int i = tid; i < 289; i += 256) adj_s[i] = adj[i];
    s16x8 af3[6];
    #pragma unroll
    for (int kk = 0; kk < 6; kk++)
        af3[kk] = *(const s16x8*)(effW3 +
            (wave * 16 + col) * 192 + kk * 32 + kgrp * 8);

    // coalesced stage: rows (t0-2 .. t0+9) x 17 k, zero-fill OOB
    {
        const int bLo = b * (T_DIM * 17);
        const int bHi = bLo + T_DIM * 17;
        const int g0r = bLo + (t0 - 2) * 17;
        for (int idx = tid; idx < 1632; idx += 256) {
            const int row = idx >> 3, c = idx & 7;
            const int gr = g0r + row;
            s16x8 v = (s16x8){0,0,0,0,0,0,0,0};
            if (gr >= bLo && gr < bHi)
                v = *(const s16x8*)(y2 + (size_t)gr * 64 + c * 8);
            *(s16x8*)&ybuf[row * 72 + c * 8] = v;
        }
    }
    __syncthreads();

    // ---- GEMM3: 136 rows (9 tiles), K=192, DIL=2, acc in regs ----
    f32x4 acc3[9];
    #pragma unroll
    for (int t3 = 0; t3 < 9; t3++) acc3[t3] = (f32x4){0.f, 0.f, 0.f, 0.f};
    #pragma unroll
    for (int kk = 0; kk < 6; kk++) {
        #pragma unroll
        for (int t3 = 0; t3 < 9; t3++) {
            const int r = t3 * 16 + col;
            const int me = r < 136 ? r : 135;
            s16x8 bfr = *(const s16x8*)&ybuf[
                (me + 34 * (kk >> 1)) * 72 + (kk & 1) * 32 + kgrp * 8];
            acc3[t3] = __builtin_amdgcn_mfma_f32_16x16x32_bf16(
                af3[kk], bfr, acc3[t3], 0, 0, 0);
        }
    }
    // residual pre-sum (rows 34..169 = y2[t0..t0+7]) -> 2 regs
    float rs0 = 0.f, rs1 = 0.f;
    {
        const int tl = tid >> 5, o0 = (tid & 31) * 2;
        #pragma unroll
        for (int v = 0; v < 17; v++) {
            unsigned u = *(const unsigned*)&ybuf[((tl + 2) * 17 + v) * 72 + o0];
            rs0 += bf2f((short)(u & 0xFFFF));
            rs1 += bf2f((short)(u >> 16));
        }
    }
    __syncthreads();

    // ---- z3 -> ybuf rows 0..135 ----
    #pragma unroll
    for (int t3 = 0; t3 < 9; t3++) {
        const int r = t3 * 16 + col;
        if (r < 136) {
            u32x2 st;
            st[0] = pk2bf(acc3[t3][0], acc3[t3][1]);
            st[1] = pk2bf(acc3[t3][2], acc3[t3][3]);
            *(u32x2*)&ybuf[r * 72 + wave * 16 + kgrp * 4] = st;
        }
    }
    __syncthreads();

    // ---- mix3 + pool ----
    {
        const int tl = tid >> 5, o0 = (tid & 31) * 2;
        const float inv0 = bnc[128 + o0], inv1 = bnc[128 + o0 + 1];
        const float sh0 = bnc[320 + o0], sh1 = bnc[320 + o0 + 1];
        float zk0[17], zk1[17];
        #pragma unroll
        for (int k = 0; k < 17; k++) {
            unsigned u = *(const unsigned*)&ybuf[(tl * 17 + k) * 72 + o0];
            zk0[k] = bf2f((short)(u & 0xFFFF));
            zk1[k] = bf2f((short)(u >> 16));
        }
        float ps0 = rs0, ps1 = rs1;
        #pragma unroll
        for (int v = 0; v < 17; v++) {
            float g0 = 0.f, g1 = 0.f;
            #pragma unroll
            for (int e = NBR_PTR[v]; e < NBR_PTR[v + 1]; e++) {
                int k = NBR_K[e];
                float w = adj_s[k * 17 + v];
                g0 += w * zk0[k]; g1 += w * zk1[k];
            }
            ps0 += fmaxf(g0 * inv0 + sh0, 0.f);
            ps1 += fmaxf(g1 * inv1 + sh1, 0.f);
        }
        *(float2*)&pr[tl * 64 + o0] = make_float2(ps0, ps1);
    }
    __syncthreads();
    if (tid < 64) {
        float s = 0.f;
        #pragma unroll
        for (int i = 0; i < 8; i++) s += pr[i * 64 + tid];
        part[((size_t)(b0 + b) * 256 + blockIdx.x) * 64 + tid] = s;
    }
}

// ---------------------------------------------------------------------------
// Sum 256 partials per (b,c) with 256 threads, mean, LayerNorm, FC.
// ---------------------------------------------------------------------------
__global__ __launch_bounds__(256) void finish_kernel(
    const float* __restrict__ part, const float* __restrict__ ln_s,
    const float* __restrict__ ln_b, const float* __restrict__ fc_w,
    const float* __restrict__ fc_b, float* __restrict__ out)
{
    __shared__ float red[4][64];
    __shared__ float ns[64];
    const int b = blockIdx.x;
    const int g = threadIdx.x >> 6, c = threadIdx.x & 63;
    float s = 0.f;
    for (int j = 0; j < 64; j++)
        s += part[((size_t)b * 256 + g * 64 + j) * 64 + c];
    red[g][c] = s;
    __syncthreads();
    if (threadIdx.x < 64) {
        float feat = (red[0][c] + red[1][c] + red[2][c] + red[3][c])
                   / (float)(T_DIM * K_DIM);
        float m = feat;
        #pragma unroll
        for (int off = 32; off > 0; off >>= 1) m += __shfl_down(m, off);
        m = __shfl(m, 0) / 64.f;
        float d = feat - m;
        float v = d * d;
        #pragma unroll
        for (int off = 32; off > 0; off >>= 1) v += __shfl_down(v, off);
        v = __shfl(v, 0) / 64.f;
        ns[c] = d * rsqrtf(v + 1e-5f) * ln_s[c] + ln_b[c];
    }
    __syncthreads();
    if (threadIdx.x < 10) {
        float o = fc_b[threadIdx.x];
        for (int i = 0; i < 64; i++) o += ns[i] * fc_w[i * 10 + threadIdx.x];
        out[b * 10 + threadIdx.x] = o;
    }
}

// ---------------------------------------------------------------------------
extern "C" void kernel_launch(void* const* d_in, const int* in_sizes, int n_in,
                              void* d_out, int out_size, void* d_ws, size_t ws_size,
                              hipStream_t stream)
{
    const float* kpts = (const float*)d_in[0];
    const float* adj  = (const float*)d_in[1];
    const float* gw0  = (const float*)d_in[2];
    const float* gw1  = (const float*)d_in[3];
    const float* gw2  = (const float*)d_in[4];
    const float* tcn  = (const float*)d_in[5];
    const float* bns  = (const float*)d_in[6];
    const float* bnb  = (const float*)d_in[7];
    const float* bnm  = (const float*)d_in[8];
    const float* bnv  = (const float*)d_in[9];
    const float* lns  = (const float*)d_in[10];
    const float* lnb  = (const float*)d_in[11];
    const float* fcw  = (const float*)d_in[12];
    const float* fcb  = (const float*)d_in[13];
    float* out = (float*)d_out;

    // ws: bnc(384 f) | part(32*256*64 f) | effT0(2048 s) | effT12(24576 s) | y2
    float* bnc  = (float*)d_ws;
    float* part = bnc + 384;
    short* effT0  = (short*)(part + (size_t)B_DIM * 256 * 64);
    short* effT12 = effT0 + 2048;
    short* y2     = effT12 + 24576;
    const size_t fixed_bytes = 384 * 4 + (size_t)B_DIM * 256 * 64 * 4
                             + 2048 * 2 + 24576 * 2;          // ~2.15 MB
    const size_t y_per_b = (size_t)T_DIM * K_DIM * 64 * 2;    // 4,456,448 B

    int cb = B_DIM;                 // single y2 buffer: cb=32 needs ~145 MB
    while (cb > 1 && fixed_bytes + (size_t)cb * y_per_b > ws_size) cb >>= 1;

    fold_weights_kernel<<<64, 256, 0, stream>>>(gw0, gw1, gw2, tcn,
                                                bns, bnb, bnm, bnv,
                                                effT0, effT12, bnc);

    for (int b0 = 0; b0 < B_DIM; b0 += cb) {
        stgcn_ab_kernel<<<dim3(T_DIM / 8, cb), 256, 0, stream>>>(
            kpts + (size_t)b0 * T_DIM * K_DIM * 3, adj, effT0, effT12, bnc, y2);
        stgcn_c_kernel<<<dim3(T_DIM / 8, cb), 256, 0, stream>>>(
            y2, adj, effT12 + 12288, bnc, part, b0);
    }

    finish_kernel<<<B_DIM, 256, 0, stream>>>(part, lns, lnb, fcw, fcb, out);
}

// Round 13
// 241.306 us; speedup vs baseline: 1.2182x; 1.1008x over previous
//
#include <hip/hip_runtime.h>
#include <hip/hip_bf16.h>
#include <math.h>

#define T_DIM 2048
#define TP_DIM 2052                  // padded t rows: tp = t + 2, 2 pad each side
#define K_DIM 17
#define HID   64
#define B_DIM 32

typedef short s16x8 __attribute__((ext_vector_type(8)));
typedef unsigned u32x2 __attribute__((ext_vector_type(2)));
typedef float f32x4 __attribute__((ext_vector_type(4)));

__device__ __forceinline__ float bf2f(short u) {
    unsigned v = ((unsigned)(unsigned short)u) << 16;
    return __builtin_bit_cast(float, v);
}
__device__ __forceinline__ short f2bf(float f) {          // cold path
    __hip_bfloat16 h = __float2bfloat16(f);
    return __builtin_bit_cast(short, h);
}
__device__ __forceinline__ short f2bf_fast(float f) {
    unsigned u = __builtin_bit_cast(unsigned, f);
    return (short)((u + 0x8000u) >> 16);
}
__device__ __forceinline__ unsigned pk2bf(float lo, float hi) {
    unsigned ul = __builtin_bit_cast(unsigned, lo);
    unsigned uh = __builtin_bit_cast(unsigned, hi);
    return ((ul + 0x8000u) >> 16) | ((uh + 0x8000u) & 0xFFFF0000u);
}

// COCO skeleton sparsity: column-v nonzeros of adj (incl. self).
static constexpr int NBR_PTR[18] = {0,3,6,9,11,13,17,21,24,27,29,31,34,37,40,43,45,47};
static constexpr int NBR_K[47] = {
    0,1,2,  0,1,3,  0,2,4,  1,3,  2,4,
    5,6,7,11,  5,6,8,12,  5,7,9,  6,8,10,  7,9,  8,10,
    5,11,13,  6,12,14,  11,13,15,  12,14,16,  13,15,  14,16 };
__device__ const int d_NBR_PTR[18] = {0,3,6,9,11,13,17,21,24,27,29,31,34,37,40,43,45,47};
__device__ const int d_NBR_K[47] = {
    0,1,2,  0,1,3,  0,2,4,  1,3,  2,4,
    5,6,7,11,  5,6,8,12,  5,7,9,  6,8,10,  7,9,  8,10,
    5,11,13,  6,12,14,  11,13,15,  12,14,16,  13,15,  14,16 };

// ---------------------------------------------------------------------------
// Fold GCN channel-mix into temporal conv weights (bf16).
// ---------------------------------------------------------------------------
__global__ void fold_weights_kernel(
    const float* __restrict__ gw0, const float* __restrict__ gw1,
    const float* __restrict__ gw2, const float* __restrict__ tcn,
    const float* __restrict__ bns, const float* __restrict__ bnb,
    const float* __restrict__ bnm, const float* __restrict__ bnv,
    short* __restrict__ effT0, short* __restrict__ effT12,
    float* __restrict__ bnc)
{
    int tid = blockIdx.x * blockDim.x + threadIdx.x;
    int stride = gridDim.x * blockDim.x;
    for (int idx = tid; idx < 2048; idx += stride) {
        int o = idx >> 5, k = idx & 31, dt = k >> 3, cin = k & 7;
        float s = 0.f;
        if (dt < 3 && cin < 3)
            for (int m = 0; m < 64; m++)
                s += gw0[cin * 64 + m] * tcn[(o * 64 + m) * 3 + dt];
        effT0[idx] = f2bf(s);
    }
    for (int idx = tid; idx < 24576; idx += stride) {
        int blk = idx / 12288;
        int r = idx - blk * 12288;
        int o = r / 192, k = r - o * 192, dt = k >> 6, c = k & 63;
        const float* gw = blk ? gw2 : gw1;
        const float* tw = tcn + (size_t)(blk + 1) * 64 * 64 * 3;
        float s = 0.f;
        for (int m = 0; m < 64; m++)
            s += gw[c * 64 + m] * tw[(o * 64 + m) * 3 + dt];
        effT12[idx] = f2bf(s);
    }
    for (int i = tid; i < 192; i += stride) {
        float inv = bns[i] * rsqrtf(bnv[i] + 1e-5f);
        bnc[i] = inv;
        bnc[192 + i] = bnb[i] - bnm[i] * inv;
    }
}

// ---------------------------------------------------------------------------
// Premix kernel: xg[b][tp][j*3+c] = sum_k adj[k][j] * x[b][tp-2][k][c],
// zero for pad rows (tp<2 or tp>=2050).  Pitch 52 floats (16B-aligned rows).
// Also zeroes y2's 4 pad t-rows per b (harness re-poisons ws each launch).
// Memory-bound (~27 MB traffic).
// ---------------------------------------------------------------------------
__global__ __launch_bounds__(256) void premix_kernel(
    const float* __restrict__ x, const float* __restrict__ adj,
    float* __restrict__ xg, short* __restrict__ y2, int cb)
{
    const int idx = blockIdx.x * 256 + threadIdx.x;
    const int total = cb * TP_DIM * K_DIM;
    if (idx < total) {
        const int b = idx / (TP_DIM * K_DIM);
        const int rem = idx - b * (TP_DIM * K_DIM);
        const int tp = rem / K_DIM, j = rem - tp * K_DIM;
        const int t = tp - 2;
        float a0 = 0.f, a1 = 0.f, a2 = 0.f;
        if (t >= 0 && t < T_DIM) {
            const float* xp = x + ((size_t)b * T_DIM + t) * 51;
            const int p0 = d_NBR_PTR[j], p1 = d_NBR_PTR[j + 1];
            for (int e = p0; e < p1; e++) {
                int k = d_NBR_K[e];
                float w = adj[k * 17 + j];
                a0 += w * xp[k * 3 + 0];
                a1 += w * xp[k * 3 + 1];
                a2 += w * xp[k * 3 + 2];
            }
        }
        float* op = xg + ((size_t)b * TP_DIM + tp) * 52 + j * 3;
        op[0] = a0; op[1] = a1; op[2] = a2;
    }
    // zero y2 pad rows: tp in {0,1,2050,2051}, 17*64 shorts each
    const int zn = cb * 4 * 1088;
    for (int z = idx; z < zn; z += gridDim.x * 256) {
        int bb = z / (4 * 1088);
        int rr = z - bb * 4 * 1088;
        int pi = rr / 1088;
        int ci = rr - pi * 1088;
        int tp = (pi < 2) ? pi : (2048 + pi);
        y2[((size_t)(bb * TP_DIM + tp) * K_DIM) * 64 + ci] = 0;
    }
}

// ---------------------------------------------------------------------------
// Kernel A: blocks 1+2 fused.  Block1 adjacency-first (premixed globally),
// block2 adjacency-last.  Phases: stage xtg (float4 copy, branch-free) |
// GEMM1 (B gathered from xtg, BN+ReLU epilogue) -> y1 in ybuf | GEMM2 acc
// regs + residual preload | z2 -> ybuf | mix2 + residual + y2 store.
// (256,4): VGPR cap 128, no spill (R11's (256,5) spilled).  LDS ~28 KB.
// ---------------------------------------------------------------------------
__global__ __launch_bounds__(256, 4) void stgcn_ab_kernel(
    const float* __restrict__ xg, const float* __restrict__ adj,
    const short* __restrict__ effT0, const short* __restrict__ effT12,
    const float* __restrict__ bnc, short* __restrict__ y2)
{
    __shared__ float adj_s[289];
    __shared__ __align__(16) float xtg[12 * 52];       // 2496 B
    __shared__ __align__(16) short ybuf[170 * 72];     // 24480 B

    const int tid = threadIdx.x;
    const int b = blockIdx.y;
    const int t0 = blockIdx.x * 8;
    const int lane = tid & 63, wave = tid >> 6;
    const int col = lane & 15, kgrp = lane >> 4;

    for (int i = tid; i < 289; i += 256) adj_s[i] = adj[i];
    {   // branch-free coalesced stage: 12 rows x 52 floats = 156 float4
        const float4* src = (const float4*)(xg + ((size_t)b * TP_DIM + t0) * 52);
        float4* dst = (float4*)xtg;
        for (int i = tid; i < 156; i += 256) dst[i] = src[i];
    }
    // weight A-frags (m-tile per wave: o = wave*16 + col)
    s16x8 af1 = *(const s16x8*)(effT0 + (wave * 16 + col) * 32 + kgrp * 8);
    s16x8 af2[6];
    #pragma unroll
    for (int kk = 0; kk < 6; kk++)
        af2[kk] = *(const s16x8*)(effT12 +
            (wave * 16 + col) * 192 + kk * 32 + kgrp * 8);
    __syncthreads();

    // ---- GEMM1: 170 rows (11 tiles), K=32; B gathered from xtg;
    //      epilogue BN+ReLU (+halo-t zero) -> y1 rows in ybuf ----
    {
        f32x4 inv4 = *(const f32x4*)&bnc[wave * 16 + kgrp * 4];
        f32x4 sh4  = *(const f32x4*)&bnc[192 + wave * 16 + kgrp * 4];
        for (int tile = 0; tile < 11; tile++) {
            const int r = tile * 16 + col;
            const int me = r < 170 ? r : 169;
            const int s = (me * 241) >> 12;     // me/17
            const int j = me - s * 17;
            s16x8 bfr = (s16x8){0,0,0,0,0,0,0,0};
            if (kgrp < 3) {                      // dt = kgrp
                const float* xp = &xtg[(s + kgrp) * 52 + j * 3];
                bfr[0] = f2bf_fast(xp[0]);
                bfr[1] = f2bf_fast(xp[1]);
                bfr[2] = f2bf_fast(xp[2]);
            }
            f32x4 acc = __builtin_amdgcn_mfma_f32_16x16x32_bf16(
                af1, bfr, (f32x4){0.f, 0.f, 0.f, 0.f}, 0, 0, 0);
            const int t = t0 - 1 + s;
            const bool valid = (t >= 0) && (t < T_DIM);
            if (r < 170) {
                float v0 = valid ? fmaxf(acc[0] * inv4[0] + sh4[0], 0.f) : 0.f;
                float v1 = valid ? fmaxf(acc[1] * inv4[1] + sh4[1], 0.f) : 0.f;
                float v2 = valid ? fmaxf(acc[2] * inv4[2] + sh4[2], 0.f) : 0.f;
                float v3 = valid ? fmaxf(acc[3] * inv4[3] + sh4[3], 0.f) : 0.f;
                u32x2 st; st[0] = pk2bf(v0, v1); st[1] = pk2bf(v2, v3);
                *(u32x2*)&ybuf[r * 72 + wave * 16 + kgrp * 4] = st;
            }
        }
    }
    __syncthreads();

    // ---- GEMM2: 136 rows (9 tiles), K=192, acc in regs ----
    f32x4 acc2[9];
    #pragma unroll
    for (int t2 = 0; t2 < 9; t2++) acc2[t2] = (f32x4){0.f, 0.f, 0.f, 0.f};
    #pragma unroll
    for (int kk = 0; kk < 6; kk++) {
        #pragma unroll
        for (int t2 = 0; t2 < 9; t2++) {
            const int r = t2 * 16 + col;
            const int me = r < 136 ? r : 135;
            s16x8 bfr = *(const s16x8*)&ybuf[
                (me + 17 * (kk >> 1)) * 72 + (kk & 1) * 32 + kgrp * 8];
            acc2[t2] = __builtin_amdgcn_mfma_f32_16x16x32_bf16(
                af2[kk], bfr, acc2[t2], 0, 0, 0);
        }
    }
    // residual preload (y1 rows 17..152) into regs before overwrite
    unsigned rv[17];
    {
        const int tl = tid >> 5, o0 = (tid & 31) * 2;
        #pragma unroll
        for (int v = 0; v < 17; v++)
            rv[v] = *(const unsigned*)&ybuf[((tl + 1) * 17 + v) * 72 + o0];
    }
    __syncthreads();

    // ---- z2 -> ybuf rows 0..135 ----
    #pragma unroll
    for (int t2 = 0; t2 < 9; t2++) {
        const int r = t2 * 16 + col;
        if (r < 136) {
            u32x2 st;
            st[0] = pk2bf(acc2[t2][0], acc2[t2][1]);
            st[1] = pk2bf(acc2[t2][2], acc2[t2][3]);
            *(u32x2*)&ybuf[r * 72 + wave * 16 + kgrp * 4] = st;
        }
    }
    __syncthreads();

    // ---- mix2 + residual + coalesced y2 store (padded tp = t+2) ----
    {
        const int tl = tid >> 5, o0 = (tid & 31) * 2;
        const float inv0 = bnc[64 + o0], inv1 = bnc[64 + o0 + 1];
        const float sh0 = bnc[256 + o0], sh1 = bnc[256 + o0 + 1];
        float zk0[17], zk1[17];
        #pragma unroll
        for (int k = 0; k < 17; k++) {
            unsigned u = *(const unsigned*)&ybuf[(tl * 17 + k) * 72 + o0];
            zk0[k] = bf2f((short)(u & 0xFFFF));
            zk1[k] = bf2f((short)(u >> 16));
        }
        const size_t gout = ((size_t)b * TP_DIM + t0 + tl + 2) * K_DIM * 64;
        #pragma unroll
        for (int v = 0; v < 17; v++) {
            float g0 = 0.f, g1 = 0.f;
            #pragma unroll
            for (int e = NBR_PTR[v]; e < NBR_PTR[v + 1]; e++) {
                int k = NBR_K[e];
                float w = adj_s[k * 17 + v];
                g0 += w * zk0[k]; g1 += w * zk1[k];
            }
            float v0 = fmaxf(g0 * inv0 + sh0, 0.f) + bf2f((short)(rv[v] & 0xFFFF));
            float v1 = fmaxf(g1 * inv1 + sh1, 0.f) + bf2f((short)(rv[v] >> 16));
            *(unsigned*)&y2[gout + (size_t)v * 64 + o0] = pk2bf(v0, v1);
        }
    }
}

// ---------------------------------------------------------------------------
// Kernel B: block 3 (DIL=2) + pool.  Branch-free coalesced stage (y2 padded),
// GEMM3 acc in regs, residual pre-sum, z3 overwrite, mix3 + pool.
// pr aliased into dead ybuf tail.  (256,4).
// ---------------------------------------------------------------------------
__global__ __launch_bounds__(256, 4) void stgcn_c_kernel(
    const short* __restrict__ y2, const float* __restrict__ adj,
    const short* __restrict__ effW3, const float* __restrict__ bnc,
    float* __restrict__ part, int b0)
{
    __shared__ float adj_s[289];
    __shared__ __align__(16) short ybuf[204 * 72];     // 29376 B

    float* pr = (float*)&ybuf[136 * 72];   // alias: rows 136.. free at pool time

    const int tid = threadIdx.x;
    const int b = blockIdx.y;
    const int t0 = blockIdx.x * 8;
    const int lane = tid & 63, wave = tid >> 6;
    const int col = lane & 15, kgrp = lane >> 4;

    for (int i = tid; i < 289; i += 256) adj_s[i] = adj[i];
    s16x8 af3[6];
    #pragma unroll
    for (int kk = 0; kk < 6; kk++)
        af3[kk] = *(const s16x8*)(effW3 +
            (wave * 16 + col) * 192 + kk * 32 + kgrp * 8);

    // branch-free coalesced stage: 204 rows (tp = t0 .. t0+11)
    {
        const short* base = y2 + ((size_t)b * TP_DIM + t0) * K_DIM * 64;
        for (int idx = tid; idx < 1632; idx += 256) {
            const int row = idx >> 3, c = idx & 7;
            *(s16x8*)&ybuf[row * 72 + c * 8] =
                *(const s16x8*)(base + (size_t)row * 64 + c * 8);
        }
    }
    __syncthreads();

    // ---- GEMM3: 136 rows (9 tiles), K=192, DIL=2, acc in regs ----
    f32x4 acc3[9];
    #pragma unroll
    for (int t3 = 0; t3 < 9; t3++) acc3[t3] = (f32x4){0.f, 0.f, 0.f, 0.f};
    #pragma unroll
    for (int kk = 0; kk < 6; kk++) {
        #pragma unroll
        for (int t3 = 0; t3 < 9; t3++) {
            const int r = t3 * 16 + col;
            const int me = r < 136 ? r : 135;
            s16x8 bfr = *(const s16x8*)&ybuf[
                (me + 34 * (kk >> 1)) * 72 + (kk & 1) * 32 + kgrp * 8];
            acc3[t3] = __builtin_amdgcn_mfma_f32_16x16x32_bf16(
                af3[kk], bfr, acc3[t3], 0, 0, 0);
        }
    }
    // residual pre-sum (rows 34..169 = y2[t0..t0+7]) -> 2 regs
    float rs0 = 0.f, rs1 = 0.f;
    {
        const int tl = tid >> 5, o0 = (tid & 31) * 2;
        #pragma unroll
        for (int v = 0; v < 17; v++) {
            unsigned u = *(const unsigned*)&ybuf[((tl + 2) * 17 + v) * 72 + o0];
            rs0 += bf2f((short)(u & 0xFFFF));
            rs1 += bf2f((short)(u >> 16));
        }
    }
    __syncthreads();

    // ---- z3 -> ybuf rows 0..135 ----
    #pragma unroll
    for (int t3 = 0; t3 < 9; t3++) {
        const int r = t3 * 16 + col;
        if (r < 136) {
            u32x2 st;
            st[0] = pk2bf(acc3[t3][0], acc3[t3][1]);
            st[1] = pk2bf(acc3[t3][2], acc3[t3][3]);
            *(u32x2*)&ybuf[r * 72 + wave * 16 + kgrp * 4] = st;
        }
    }
    __syncthreads();

    // ---- mix3 + pool ----
    {
        const int tl = tid >> 5, o0 = (tid & 31) * 2;
        const float inv0 = bnc[128 + o0], inv1 = bnc[128 + o0 + 1];
        const float sh0 = bnc[320 + o0], sh1 = bnc[320 + o0 + 1];
        float zk0[17], zk1[17];
        #pragma unroll
        for (int k = 0; k < 17; k++) {
            unsigned u = *(const unsigned*)&ybuf[(tl * 17 + k) * 72 + o0];
            zk0[k] = bf2f((short)(u & 0xFFFF));
            zk1[k] = bf2f((short)(u >> 16));
        }
        float ps0 = rs0, ps1 = rs1;
        #pragma unroll
        for (int v = 0; v < 17; v++) {
            float g0 = 0.f, g1 = 0.f;
            #pragma unroll
            for (int e = NBR_PTR[v]; e < NBR_PTR[v + 1]; e++) {
                int k = NBR_K[e];
                float w = adj_s[k * 17 + v];
                g0 += w * zk0[k]; g1 += w * zk1[k];
            }
            ps0 += fmaxf(g0 * inv0 + sh0, 0.f);
            ps1 += fmaxf(g1 * inv1 + sh1, 0.f);
        }
        *(float2*)&pr[tl * 64 + o0] = make_float2(ps0, ps1);
    }
    __syncthreads();
    if (tid < 64) {
        float s = 0.f;
        #pragma unroll
        for (int i = 0; i < 8; i++) s += pr[i * 64 + tid];
        part[((size_t)(b0 + b) * 256 + blockIdx.x) * 64 + tid] = s;
    }
}

// ---------------------------------------------------------------------------
// Sum 256 partials per (b,c) with 256 threads, mean, LayerNorm, FC.
// ---------------------------------------------------------------------------
__global__ __launch_bounds__(256) void finish_kernel(
    const float* __restrict__ part, const float* __restrict__ ln_s,
    const float* __restrict__ ln_b, const float* __restrict__ fc_w,
    const float* __restrict__ fc_b, float* __restrict__ out)
{
    __shared__ float red[4][64];
    __shared__ float ns[64];
    const int b = blockIdx.x;
    const int g = threadIdx.x >> 6, c = threadIdx.x & 63;
    float s = 0.f;
    for (int j = 0; j < 64; j++)
        s += part[((size_t)b * 256 + g * 64 + j) * 64 + c];
    red[g][c] = s;
    __syncthreads();
    if (threadIdx.x < 64) {
        float feat = (red[0][c] + red[1][c] + red[2][c] + red[3][c])
                   / (float)(T_DIM * K_DIM);
        float m = feat;
        #pragma unroll
        for (int off = 32; off > 0; off >>= 1) m += __shfl_down(m, off);
        m = __shfl(m, 0) / 64.f;
        float d = feat - m;
        float v = d * d;
        #pragma unroll
        for (int off = 32; off > 0; off >>= 1) v += __shfl_down(v, off);
        v = __shfl(v, 0) / 64.f;
        ns[c] = d * rsqrtf(v + 1e-5f) * ln_s[c] + ln_b[c];
    }
    __syncthreads();
    if (threadIdx.x < 10) {
        float o = fc_b[threadIdx.x];
        for (int i = 0; i < 64; i++) o += ns[i] * fc_w[i * 10 + threadIdx.x];
        out[b * 10 + threadIdx.x] = o;
    }
}

// ---------------------------------------------------------------------------
extern "C" void kernel_launch(void* const* d_in, const int* in_sizes, int n_in,
                              void* d_out, int out_size, void* d_ws, size_t ws_size,
                              hipStream_t stream)
{
    const float* kpts = (const float*)d_in[0];
    const float* adj  = (const float*)d_in[1];
    const float* gw0  = (const float*)d_in[2];
    const float* gw1  = (const float*)d_in[3];
    const float* gw2  = (const float*)d_in[4];
    const float* tcn  = (const float*)d_in[5];
    const float* bns  = (const float*)d_in[6];
    const float* bnb  = (const float*)d_in[7];
    const float* bnm  = (const float*)d_in[8];
    const float* bnv  = (const float*)d_in[9];
    const float* lns  = (const float*)d_in[10];
    const float* lnb  = (const float*)d_in[11];
    const float* fcw  = (const float*)d_in[12];
    const float* fcb  = (const float*)d_in[13];
    float* out = (float*)d_out;

    // ws: bnc | part | effT0 | effT12 | xg (padded) | y2 (padded)
    float* bnc  = (float*)d_ws;
    float* part = bnc + 384;
    short* effT0  = (short*)(part + (size_t)B_DIM * 256 * 64);
    short* effT12 = effT0 + 2048;
    float* xg     = (float*)(effT12 + 24576);
    const size_t fixed_bytes = 384 * 4 + (size_t)B_DIM * 256 * 64 * 4
                             + 2048 * 2 + 24576 * 2;
    const size_t xg_per_b = (size_t)TP_DIM * 52 * 4;            // 426,816 B
    const size_t y2_per_b = (size_t)TP_DIM * K_DIM * 64 * 2;    // 4,465,152 B

    int cb = B_DIM;
    while (cb > 1 &&
           fixed_bytes + (size_t)cb * (xg_per_b + y2_per_b) > ws_size)
        cb >>= 1;
    short* y2 = (short*)(xg + (size_t)cb * TP_DIM * 52);

    fold_weights_kernel<<<64, 256, 0, stream>>>(gw0, gw1, gw2, tcn,
                                                bns, bnb, bnm, bnv,
                                                effT0, effT12, bnc);

    const int pm_blocks = (cb * TP_DIM * K_DIM + 255) / 256;
    for (int b0 = 0; b0 < B_DIM; b0 += cb) {
        premix_kernel<<<pm_blocks, 256, 0, stream>>>(
            kpts + (size_t)b0 * T_DIM * K_DIM * 3, adj, xg, y2, cb);
        stgcn_ab_kernel<<<dim3(T_DIM / 8, cb), 256, 0, stream>>>(
            xg, adj, effT0, effT12, bnc, y2);
        stgcn_c_kernel<<<dim3(T_DIM / 8, cb), 256, 0, stream>>>(
            y2, adj, effT12 + 12288, bnc, part, b0);
    }

    finish_kernel<<<B_DIM, 256, 0, stream>>>(part, lns, lnb, fcw, fcb, out);
}

// Round 16
// 227.327 us; speedup vs baseline: 1.2931x; 1.0615x over previous
//
#include <hip/hip_runtime.h>
#include <hip/hip_fp16.h>
#include <math.h>

#define T_DIM 2048
#define TP_DIM 2052                  // padded t rows: tp = t + 2, 2 pad each side
#define K_DIM 17
#define HID   64
#define B_DIM 32

typedef short s16x8 __attribute__((ext_vector_type(8)));
typedef unsigned u32x2 __attribute__((ext_vector_type(2)));
typedef float f32x4 __attribute__((ext_vector_type(4)));
typedef _Float16 f16x2 __attribute__((ext_vector_type(2)));

// packed f32 pair -> f16 pair (1 instruction: v_cvt_pkrtz_f16_f32)
__device__ __forceinline__ unsigned pkh(float lo, float hi) {
    return __builtin_bit_cast(unsigned, __builtin_amdgcn_cvt_pkrtz(lo, hi));
}
__device__ __forceinline__ f16x2 u2h(unsigned v) {
    return __builtin_bit_cast(f16x2, v);
}
__device__ __forceinline__ unsigned h2u(f16x2 v) {
    return __builtin_bit_cast(unsigned, v);
}
__device__ __forceinline__ short f2h(float f) {          // cold path
    _Float16 h = (_Float16)f;
    return __builtin_bit_cast(short, h);
}

// COCO skeleton sparsity: column-v nonzeros of adj (incl. self).
static constexpr int NBR_PTR[18] = {0,3,6,9,11,13,17,21,24,27,29,31,34,37,40,43,45,47};
static constexpr int NBR_K[47] = {
    0,1,2,  0,1,3,  0,2,4,  1,3,  2,4,
    5,6,7,11,  5,6,8,12,  5,7,9,  6,8,10,  7,9,  8,10,
    5,11,13,  6,12,14,  11,13,15,  12,14,16,  13,15,  14,16 };
__device__ const int d_NBR_PTR[18] = {0,3,6,9,11,13,17,21,24,27,29,31,34,37,40,43,45,47};
__device__ const int d_NBR_K[47] = {
    0,1,2,  0,1,3,  0,2,4,  1,3,  2,4,
    5,6,7,11,  5,6,8,12,  5,7,9,  6,8,10,  7,9,  8,10,
    5,11,13,  6,12,14,  11,13,15,  12,14,16,  13,15,  14,16 };

// ---------------------------------------------------------------------------
// Fold GCN channel-mix into temporal conv weights (f16).
//   effT0[o][k32]  k = dt*8+cin (cin<3, dt<3), rest 0    (block1, K=32)
//   effT12[blk][o][dt*64+c]                              (blocks 2,3, K=192)
//   bnc[blk*64+o] = s/sqrt(v+eps);  bnc[192+blk*64+o] = b - m*inv
// ---------------------------------------------------------------------------
__global__ void fold_weights_kernel(
    const float* __restrict__ gw0, const float* __restrict__ gw1,
    const float* __restrict__ gw2, const float* __restrict__ tcn,
    const float* __restrict__ bns, const float* __restrict__ bnb,
    const float* __restrict__ bnm, const float* __restrict__ bnv,
    short* __restrict__ effT0, short* __restrict__ effT12,
    float* __restrict__ bnc)
{
    int tid = blockIdx.x * blockDim.x + threadIdx.x;
    int stride = gridDim.x * blockDim.x;
    for (int idx = tid; idx < 2048; idx += stride) {
        int o = idx >> 5, k = idx & 31, dt = k >> 3, cin = k & 7;
        float s = 0.f;
        if (dt < 3 && cin < 3)
            for (int m = 0; m < 64; m++)
                s += gw0[cin * 64 + m] * tcn[(o * 64 + m) * 3 + dt];
        effT0[idx] = f2h(s);
    }
    for (int idx = tid; idx < 24576; idx += stride) {
        int blk = idx / 12288;
        int r = idx - blk * 12288;
        int o = r / 192, k = r - o * 192, dt = k >> 6, c = k & 63;
        const float* gw = blk ? gw2 : gw1;
        const float* tw = tcn + (size_t)(blk + 1) * 64 * 64 * 3;
        float s = 0.f;
        for (int m = 0; m < 64; m++)
            s += gw[c * 64 + m] * tw[(o * 64 + m) * 3 + dt];
        effT12[idx] = f2h(s);
    }
    for (int i = tid; i < 192; i += stride) {
        float inv = bns[i] * rsqrtf(bnv[i] + 1e-5f);
        bnc[i] = inv;
        bnc[192 + i] = bnb[i] - bnm[i] * inv;
    }
}

// ---------------------------------------------------------------------------
// Premix kernel: xg[b][tp][j*3+c] = sum_k adj[k][j] * x[b][tp-2][k][c],
// zero for pad rows.  Pitch 52 floats.  Also zeroes y2's 4 pad t-rows per b.
// ---------------------------------------------------------------------------
__global__ __launch_bounds__(256) void premix_kernel(
    const float* __restrict__ x, const float* __restrict__ adj,
    float* __restrict__ xg, short* __restrict__ y2, int cb)
{
    const int idx = blockIdx.x * 256 + threadIdx.x;
    const int total = cb * TP_DIM * K_DIM;
    if (idx < total) {
        const int b = idx / (TP_DIM * K_DIM);
        const int rem = idx - b * (TP_DIM * K_DIM);
        const int tp = rem / K_DIM, j = rem - tp * K_DIM;
        const int t = tp - 2;
        float a0 = 0.f, a1 = 0.f, a2 = 0.f;
        if (t >= 0 && t < T_DIM) {
            const float* xp = x + ((size_t)b * T_DIM + t) * 51;
            const int p0 = d_NBR_PTR[j], p1 = d_NBR_PTR[j + 1];
            for (int e = p0; e < p1; e++) {
                int k = d_NBR_K[e];
                float w = adj[k * 17 + j];
                a0 += w * xp[k * 3 + 0];
                a1 += w * xp[k * 3 + 1];
                a2 += w * xp[k * 3 + 2];
            }
        }
        float* op = xg + ((size_t)b * TP_DIM + tp) * 52 + j * 3;
        op[0] = a0; op[1] = a1; op[2] = a2;
    }
    // zero y2 pad rows: tp in {0,1,2050,2051}, 17*64 shorts each
    const int zn = cb * 4 * 1088;
    for (int z = idx; z < zn; z += gridDim.x * 256) {
        int bb = z / (4 * 1088);
        int rr = z - bb * 4 * 1088;
        int pi = rr / 1088;
        int ci = rr - pi * 1088;
        int tp = (pi < 2) ? pi : (2048 + pi);
        y2[((size_t)(bb * TP_DIM + tp) * K_DIM) * 64 + ci] = 0;
    }
}

// ---------------------------------------------------------------------------
// Kernel A: blocks 1+2 fused, f16 pipeline.  Block1 adjacency-first
// (premixed globally), block2 adjacency-last with packed-f16 mix
// (native f16x2 arithmetic -> v_pk_fma_f16).
// (256,4): VGPR cap 128, no spill.
// ---------------------------------------------------------------------------
__global__ __launch_bounds__(256, 4) void stgcn_ab_kernel(
    const float* __restrict__ xg, const float* __restrict__ adj,
    const short* __restrict__ effT0, const short* __restrict__ effT12,
    const float* __restrict__ bnc, short* __restrict__ y2)
{
    __shared__ unsigned adj_h[289];                    // f16x2 broadcast pairs
    __shared__ __align__(16) float xtg[12 * 52];       // 2496 B
    __shared__ __align__(16) short ybuf[170 * 72];     // 24480 B

    const int tid = threadIdx.x;
    const int b = blockIdx.y;
    const int t0 = blockIdx.x * 8;
    const int lane = tid & 63, wave = tid >> 6;
    const int col = lane & 15, kgrp = lane >> 4;

    for (int i = tid; i < 289; i += 256) {
        float w = adj[i];
        adj_h[i] = pkh(w, w);
    }
    {   // branch-free coalesced stage: 12 rows x 52 floats = 156 float4
        const float4* src = (const float4*)(xg + ((size_t)b * TP_DIM + t0) * 52);
        float4* dst = (float4*)xtg;
        for (int i = tid; i < 156; i += 256) dst[i] = src[i];
    }
    // weight A-frags (m-tile per wave: o = wave*16 + col)
    s16x8 af1 = *(const s16x8*)(effT0 + (wave * 16 + col) * 32 + kgrp * 8);
    s16x8 af2[6];
    #pragma unroll
    for (int kk = 0; kk < 6; kk++)
        af2[kk] = *(const s16x8*)(effT12 +
            (wave * 16 + col) * 192 + kk * 32 + kgrp * 8);
    __syncthreads();

    // ---- GEMM1: 170 rows (11 tiles), K=32; B gathered from xtg;
    //      epilogue BN+ReLU (+halo-t zero) -> y1 rows in ybuf ----
    {
        f32x4 inv4 = *(const f32x4*)&bnc[wave * 16 + kgrp * 4];
        f32x4 sh4  = *(const f32x4*)&bnc[192 + wave * 16 + kgrp * 4];
        for (int tile = 0; tile < 11; tile++) {
            const int r = tile * 16 + col;
            const int me = r < 170 ? r : 169;
            const int s = (me * 241) >> 12;     // me/17
            const int j = me - s * 17;
            int4 bz = {0, 0, 0, 0};
            if (kgrp < 3) {                      // dt = kgrp
                const float* xp = &xtg[(s + kgrp) * 52 + j * 3];
                bz.x = (int)pkh(xp[0], xp[1]);
                bz.y = (int)pkh(xp[2], 0.f);
            }
            s16x8 bfr = __builtin_bit_cast(s16x8, bz);
            f32x4 acc = __builtin_amdgcn_mfma_f32_16x16x32_f16(
                af1, bfr, (f32x4){0.f, 0.f, 0.f, 0.f}, 0, 0, 0);
            const int t = t0 - 1 + s;
            const bool valid = (t >= 0) && (t < T_DIM);
            if (r < 170) {
                float v0 = valid ? fmaxf(acc[0] * inv4[0] + sh4[0], 0.f) : 0.f;
                float v1 = valid ? fmaxf(acc[1] * inv4[1] + sh4[1], 0.f) : 0.f;
                float v2 = valid ? fmaxf(acc[2] * inv4[2] + sh4[2], 0.f) : 0.f;
                float v3 = valid ? fmaxf(acc[3] * inv4[3] + sh4[3], 0.f) : 0.f;
                u32x2 st; st[0] = pkh(v0, v1); st[1] = pkh(v2, v3);
                *(u32x2*)&ybuf[r * 72 + wave * 16 + kgrp * 4] = st;
            }
        }
    }
    __syncthreads();

    // ---- GEMM2: 136 rows (9 tiles), K=192, acc in regs ----
    f32x4 acc2[9];
    #pragma unroll
    for (int t2 = 0; t2 < 9; t2++) acc2[t2] = (f32x4){0.f, 0.f, 0.f, 0.f};
    #pragma unroll
    for (int kk = 0; kk < 6; kk++) {
        #pragma unroll
        for (int t2 = 0; t2 < 9; t2++) {
            const int r = t2 * 16 + col;
            const int me = r < 136 ? r : 135;
            s16x8 bfr = *(const s16x8*)&ybuf[
                (me + 17 * (kk >> 1)) * 72 + (kk & 1) * 32 + kgrp * 8];
            acc2[t2] = __builtin_amdgcn_mfma_f32_16x16x32_f16(
                af2[kk], bfr, acc2[t2], 0, 0, 0);
        }
    }
    // residual preload (y1 rows 17..152) into regs before overwrite
    unsigned rv[17];
    {
        const int tl = tid >> 5, o0 = (tid & 31) * 2;
        #pragma unroll
        for (int v = 0; v < 17; v++)
            rv[v] = *(const unsigned*)&ybuf[((tl + 1) * 17 + v) * 72 + o0];
    }
    __syncthreads();

    // ---- z2 -> ybuf rows 0..135 ----
    #pragma unroll
    for (int t2 = 0; t2 < 9; t2++) {
        const int r = t2 * 16 + col;
        if (r < 136) {
            u32x2 st;
            st[0] = pkh(acc2[t2][0], acc2[t2][1]);
            st[1] = pkh(acc2[t2][2], acc2[t2][3]);
            *(u32x2*)&ybuf[r * 72 + wave * 16 + kgrp * 4] = st;
        }
    }
    __syncthreads();

    // ---- mix2 (packed f16) + residual + coalesced y2 store (tp = t+2) ----
    {
        const int tl = tid >> 5, o0 = (tid & 31) * 2;
        const f16x2 inv2 = u2h(pkh(bnc[64 + o0], bnc[64 + o0 + 1]));
        const f16x2 sh2  = u2h(pkh(bnc[256 + o0], bnc[256 + o0 + 1]));
        const f16x2 zero = u2h(0u);
        f16x2 zk[17];
        #pragma unroll
        for (int k = 0; k < 17; k++)
            zk[k] = u2h(*(const unsigned*)&ybuf[(tl * 17 + k) * 72 + o0]);
        const size_t gout = ((size_t)b * TP_DIM + t0 + tl + 2) * K_DIM * 64;
        #pragma unroll
        for (int v = 0; v < 17; v++) {
            f16x2 g = zero;
            #pragma unroll
            for (int e = NBR_PTR[v]; e < NBR_PTR[v + 1]; e++) {
                int k = NBR_K[e];
                g = u2h(adj_h[k * 17 + v]) * zk[k] + g;
            }
            f16x2 val = __builtin_elementwise_max(g * inv2 + sh2, zero);
            val = val + u2h(rv[v]);
            *(unsigned*)&y2[gout + (size_t)v * 64 + o0] = h2u(val);
        }
    }
}

// ---------------------------------------------------------------------------
// Kernel B: block 3 (DIL=2) + pool, f16 pipeline.  Branch-free stage,
// GEMM3 acc regs, packed residual pre-sum, z3 overwrite, packed mix3 + pool.
// pr aliased into dead ybuf tail.  (256,4).
// ---------------------------------------------------------------------------
__global__ __launch_bounds__(256, 4) void stgcn_c_kernel(
    const short* __restrict__ y2, const float* __restrict__ adj,
    const short* __restrict__ effW3, const float* __restrict__ bnc,
    float* __restrict__ part, int b0)
{
    __shared__ unsigned adj_h[289];
    __shared__ __align__(16) short ybuf[204 * 72];     // 29376 B

    float* pr = (float*)&ybuf[136 * 72];   // alias: rows 136.. free at pool time

    const int tid = threadIdx.x;
    const int b = blockIdx.y;
    const int t0 = blockIdx.x * 8;
    const int lane = tid & 63, wave = tid >> 6;
    const int col = lane & 15, kgrp = lane >> 4;

    for (int i = tid; i < 289; i += 256) {
        float w = adj[i];
        adj_h[i] = pkh(w, w);
    }
    s16x8 af3[6];
    #pragma unroll
    for (int kk = 0; kk < 6; kk++)
        af3[kk] = *(const s16x8*)(effW3 +
            (wave * 16 + col) * 192 + kk * 32 + kgrp * 8);

    // branch-free coalesced stage: 204 rows (tp = t0 .. t0+11)
    {
        const short* base = y2 + ((size_t)b * TP_DIM + t0) * K_DIM * 64;
        for (int idx = tid; idx < 1632; idx += 256) {
            const int row = idx >> 3, c = idx & 7;
            *(s16x8*)&ybuf[row * 72 + c * 8] =
                *(const s16x8*)(base + (size_t)row * 64 + c * 8);
        }
    }
    __syncthreads();

    // ---- GEMM3: 136 rows (9 tiles), K=192, DIL=2, acc in regs ----
    f32x4 acc3[9];
    #pragma unroll
    for (int t3 = 0; t3 < 9; t3++) acc3[t3] = (f32x4){0.f, 0.f, 0.f, 0.f};
    #pragma unroll
    for (int kk = 0; kk < 6; kk++) {
        #pragma unroll
        for (int t3 = 0; t3 < 9; t3++) {
            const int r = t3 * 16 + col;
            const int me = r < 136 ? r : 135;
            s16x8 bfr = *(const s16x8*)&ybuf[
                (me + 34 * (kk >> 1)) * 72 + (kk & 1) * 32 + kgrp * 8];
            acc3[t3] = __builtin_amdgcn_mfma_f32_16x16x32_f16(
                af3[kk], bfr, acc3[t3], 0, 0, 0);
        }
    }
    // residual pre-sum (rows 34..169 = y2[t0..t0+7]), packed f16
    f16x2 rs = u2h(0u);
    {
        const int tl = tid >> 5, o0 = (tid & 31) * 2;
        #pragma unroll
        for (int v = 0; v < 17; v++)
            rs = rs + u2h(*(const unsigned*)&ybuf[((tl + 2) * 17 + v) * 72 + o0]);
    }
    __syncthreads();

    // ---- z3 -> ybuf rows 0..135 ----
    #pragma unroll
    for (int t3 = 0; t3 < 9; t3++) {
        const int r = t3 * 16 + col;
        if (r < 136) {
            u32x2 st;
            st[0] = pkh(acc3[t3][0], acc3[t3][1]);
            st[1] = pkh(acc3[t3][2], acc3[t3][3]);
            *(u32x2*)&ybuf[r * 72 + wave * 16 + kgrp * 4] = st;
        }
    }
    __syncthreads();

    // ---- mix3 (packed f16) + pool ----
    {
        const int tl = tid >> 5, o0 = (tid & 31) * 2;
        const f16x2 inv2 = u2h(pkh(bnc[128 + o0], bnc[128 + o0 + 1]));
        const f16x2 sh2  = u2h(pkh(bnc[320 + o0], bnc[320 + o0 + 1]));
        const f16x2 zero = u2h(0u);
        f16x2 zk[17];
        #pragma unroll
        for (int k = 0; k < 17; k++)
            zk[k] = u2h(*(const unsigned*)&ybuf[(tl * 17 + k) * 72 + o0]);
        float ps0 = (float)rs[0], ps1 = (float)rs[1];
        #pragma unroll
        for (int v = 0; v < 17; v++) {
            f16x2 g = zero;
            #pragma unroll
            for (int e = NBR_PTR[v]; e < NBR_PTR[v + 1]; e++) {
                int k = NBR_K[e];
                g = u2h(adj_h[k * 17 + v]) * zk[k] + g;
            }
            f16x2 val = __builtin_elementwise_max(g * inv2 + sh2, zero);
            ps0 += (float)val[0];
            ps1 += (float)val[1];
        }
        *(float2*)&pr[tl * 64 + o0] = make_float2(ps0, ps1);
    }
    __syncthreads();
    if (tid < 64) {
        float s = 0.f;
        #pragma unroll
        for (int i = 0; i < 8; i++) s += pr[i * 64 + tid];
        part[((size_t)(b0 + b) * 256 + blockIdx.x) * 64 + tid] = s;
    }
}

// ---------------------------------------------------------------------------
// Sum 256 partials per (b,c) with 256 threads, mean, LayerNorm, FC.
// ---------------------------------------------------------------------------
__global__ __launch_bounds__(256) void finish_kernel(
    const float* __restrict__ part, const float* __restrict__ ln_s,
    const float* __restrict__ ln_b, const float* __restrict__ fc_w,
    const float* __restrict__ fc_b, float* __restrict__ out)
{
    __shared__ float red[4][64];
    __shared__ float ns[64];
    const int b = blockIdx.x;
    const int g = threadIdx.x >> 6, c = threadIdx.x & 63;
    float s = 0.f;
    for (int j = 0; j < 64; j++)
        s += part[((size_t)b * 256 + g * 64 + j) * 64 + c];
    red[g][c] = s;
    __syncthreads();
    if (threadIdx.x < 64) {
        float feat = (red[0][c] + red[1][c] + red[2][c] + red[3][c])
                   / (float)(T_DIM * K_DIM);
        float m = feat;
        #pragma unroll
        for (int off = 32; off > 0; off >>= 1) m += __shfl_down(m, off);
        m = __shfl(m, 0) / 64.f;
        float d = feat - m;
        float v = d * d;
        #pragma unroll
        for (int off = 32; off > 0; off >>= 1) v += __shfl_down(v, off);
        v = __shfl(v, 0) / 64.f;
        ns[c] = d * rsqrtf(v + 1e-5f) * ln_s[c] + ln_b[c];
    }
    __syncthreads();
    if (threadIdx.x < 10) {
        float o = fc_b[threadIdx.x];
        for (int i = 0; i < 64; i++) o += ns[i] * fc_w[i * 10 + threadIdx.x];
        out[b * 10 + threadIdx.x] = o;
    }
}

// ---------------------------------------------------------------------------
extern "C" void kernel_launch(void* const* d_in, const int* in_sizes, int n_in,
                              void* d_out, int out_size, void* d_ws, size_t ws_size,
                              hipStream_t stream)
{
    const float* kpts = (const float*)d_in[0];
    const float* adj  = (const float*)d_in[1];
    const float* gw0  = (const float*)d_in[2];
    const float* gw1  = (const float*)d_in[3];
    const float* gw2  = (const float*)d_in[4];
    const float* tcn  = (const float*)d_in[5];
    const float* bns  = (const float*)d_in[6];
    const float* bnb  = (const float*)d_in[7];
    const float* bnm  = (const float*)d_in[8];
    const float* bnv  = (const float*)d_in[9];
    const float* lns  = (const float*)d_in[10];
    const float* lnb  = (const float*)d_in[11];
    const float* fcw  = (const float*)d_in[12];
    const float* fcb  = (const float*)d_in[13];
    float* out = (float*)d_out;

    // ws: bnc | part | effT0 | effT12 | xg (padded) | y2 (padded)
    float* bnc  = (float*)d_ws;
    float* part = bnc + 384;
    short* effT0  = (short*)(part + (size_t)B_DIM * 256 * 64);
    short* effT12 = effT0 + 2048;
    float* xg     = (float*)(effT12 + 24576);
    const size_t fixed_bytes = 384 * 4 + (size_t)B_DIM * 256 * 64 * 4
                             + 2048 * 2 + 24576 * 2;
    const size_t xg_per_b = (size_t)TP_DIM * 52 * 4;            // 426,816 B
    const size_t y2_per_b = (size_t)TP_DIM * K_DIM * 64 * 2;    // 4,465,152 B

    int cb = B_DIM;
    while (cb > 1 &&
           fixed_bytes + (size_t)cb * (xg_per_b + y2_per_b) > ws_size)
        cb >>= 1;
    short* y2 = (short*)(xg + (size_t)cb * TP_DIM * 52);

    fold_weights_kernel<<<64, 256, 0, stream>>>(gw0, gw1, gw2, tcn,
                                                bns, bnb, bnm, bnv,
                                                effT0, effT12, bnc);

    const int pm_blocks = (cb * TP_DIM * K_DIM + 255) / 256;
    for (int b0 = 0; b0 < B_DIM; b0 += cb) {
        premix_kernel<<<pm_blocks, 256, 0, stream>>>(
            kpts + (size_t)b0 * T_DIM * K_DIM * 3, adj, xg, y2, cb);
        stgcn_ab_kernel<<<dim3(T_DIM / 8, cb), 256, 0, stream>>>(
            xg, adj, effT0, effT12, bnc, y2);
        stgcn_c_kernel<<<dim3(T_DIM / 8, cb), 256, 0, stream>>>(
            y2, adj, effT12 + 12288, bnc, part, b0);
    }

    finish_kernel<<<B_DIM, 256, 0, stream>>>(part, lns, lnb, fcw, fcb, out);
}